// Round 3
// baseline (131.698 us; speedup 1.0000x reference)
//
#include <hip/hip_runtime.h>

typedef unsigned short u16;
typedef float  f32x4  __attribute__((ext_vector_type(4)));
typedef int    i32x4  __attribute__((ext_vector_type(4)));
typedef __bf16 bf16x8 __attribute__((ext_vector_type(8)));

#define AS1 __attribute__((address_space(1)))
#define AS3 __attribute__((address_space(3)))

__device__ __forceinline__ void gload_lds16(const void* g, void* l) {
  __builtin_amdgcn_global_load_lds((AS1 void*)g, (AS3 void*)l, 16, 0, 0);
}

// Problem constants
constexpr int B_ = 8, T_ = 128, U_ = 64, D_ = 512, V_ = 1024;
constexpr int M_ = B_ * T_ * U_;   // 65536

// ---------------------------------------------------------------------------
// prep: W (V,D) f32 -> bf16 in ws, LDS XOR-swizzle pre-applied per 64-col
// K-tile (16B chunk c stored at c ^ (v&7)) so the GEMM can global_load_lds
// linearly and read with the same XOR.
// ---------------------------------------------------------------------------
__global__ void prep_w(const float* __restrict__ W, u16* __restrict__ Wb) {
  const int tid = blockIdx.x * 256 + threadIdx.x;   // 65536 threads
  const int v  = tid >> 6;
  const int cs = tid & 63;
  const int g  = cs >> 3, cl = cs & 7;
  const float* sp = W + (size_t)v * D_ + cs * 8;
  float4 w0 = *(const float4*)sp;
  float4 w1 = *(const float4*)(sp + 4);
  union { __bf16 h[8]; i32x4 x; } pk;
  pk.h[0] = (__bf16)w0.x; pk.h[1] = (__bf16)w0.y;
  pk.h[2] = (__bf16)w0.z; pk.h[3] = (__bf16)w0.w;
  pk.h[4] = (__bf16)w1.x; pk.h[5] = (__bf16)w1.y;
  pk.h[6] = (__bf16)w1.z; pk.h[7] = (__bf16)w1.w;
  const int dc = g * 8 + (cl ^ (v & 7));
  *(i32x4*)(Wb + (size_t)v * D_ + dc * 8) = pk.x;
}

// lengths pass-through as f32 values
__global__ void tail_k(const int* __restrict__ sl, const int* __restrict__ tl,
                       float* __restrict__ tail) {
  const int t = threadIdx.x;
  if (t < 8)       tail[t] = (float)sl[t];
  else if (t < 16) tail[t] = (float)tl[t - 8];
}

// ---------------------------------------------------------------------------
// Fused joiner GEMM — 256x256 8-wave phase-split template (T3+T4+T5):
// BM=BN=256, BK=64, 512 threads (8 waves 2Mx4N), wave tile 128x64.
// 128 KB double-buffered LDS, 1 block/CU. 4 phases per K-tile, each:
// {ds_read quadrant frags; staging piece; s_barrier; setprio(1); 16 MFMA;
//  setprio(0); [staging piece]; s_barrier}. Buffer flip via __syncthreads
// (its vmcnt(0) drain is cheap: B-DMA was issued 3 phases earlier).
// ---------------------------------------------------------------------------
template<int USE_WS>
__global__ __launch_bounds__(512, 2) void joiner_gemm(
    const float* __restrict__ src, const float* __restrict__ tgt,
    const u16* __restrict__ Wb, const float* __restrict__ Wf,
    const float* __restrict__ bias, float* __restrict__ out)
{
  __shared__ __align__(16) char As[2][32768];   // 256 rows x 64 bf16, dbuf
  __shared__ __align__(16) char Bs[2][32768];

  const int tid  = threadIdx.x;
  const int lane = tid & 63;
  const int wid  = tid >> 6;
  const int bm   = blockIdx.x & 255;   // M-tile (fast-varying)
  const int bn   = blockIdx.x >> 8;    // N-tile 0..3
  const int bt0  = bm * 4;             // four (b,t) rows per 256-row M-tile
  const int bb   = bm >> 5;            // batch (4 rows never cross batch)
  const int sr0  = tid >> 3;           // u index 0..63
  const int sc8  = tid & 7;            // 16B k-chunk 0..7
  const int wm   = (wid >> 2) * 128;   // wave M offset
  const int wn   = (wid & 3) * 64;     // wave N offset

  f32x4 acc[8][4] = {};

  const float* srcT = src + (size_t)bt0 * D_ + sc8 * 8;
  const float* tgtT = tgt + ((size_t)bb * U_ + sr0) * D_ + sc8 * 8;

  float bv[4];
  #pragma unroll
  for (int ni = 0; ni < 4; ++ni)
    bv[ni] = bias[bn * 256 + wn + ni * 16 + (lane & 15)];

  float4 pS[8], pT[2];   // A prefetch regs (held one phase)

  auto loadA = [&](int kt) {
    const int k0 = kt * 64;
    #pragma unroll
    for (int i = 0; i < 4; ++i) {
      pS[2 * i]     = *(const float4*)(srcT + (size_t)i * D_ + k0);
      pS[2 * i + 1] = *(const float4*)(srcT + (size_t)i * D_ + k0 + 4);
    }
    pT[0] = *(const float4*)(tgtT + k0);
    pT[1] = *(const float4*)(tgtT + k0 + 4);
  };

  auto expandA = [&](int nb) {
    #pragma unroll
    for (int i = 0; i < 4; ++i) {
      const int r = i * 64 + sr0;
      union { __bf16 h[8]; i32x4 x; } pk;
      pk.h[0] = (__bf16)fmaxf(pS[2 * i].x     + pT[0].x, 0.f);
      pk.h[1] = (__bf16)fmaxf(pS[2 * i].y     + pT[0].y, 0.f);
      pk.h[2] = (__bf16)fmaxf(pS[2 * i].z     + pT[0].z, 0.f);
      pk.h[3] = (__bf16)fmaxf(pS[2 * i].w     + pT[0].w, 0.f);
      pk.h[4] = (__bf16)fmaxf(pS[2 * i + 1].x + pT[1].x, 0.f);
      pk.h[5] = (__bf16)fmaxf(pS[2 * i + 1].y + pT[1].y, 0.f);
      pk.h[6] = (__bf16)fmaxf(pS[2 * i + 1].z + pT[1].z, 0.f);
      pk.h[7] = (__bf16)fmaxf(pS[2 * i + 1].w + pT[1].w, 0.f);
      *(i32x4*)(As[nb] + r * 128 + ((sc8 ^ (r & 7)) << 4)) = pk.x;
    }
  };

  auto issueB = [&](int kt, int nb) {
    #pragma unroll
    for (int q = 0; q < 4; ++q) {
      const int i    = wid * 4 + q;             // 32 x 1KB stripes
      const int vloc = i * 8 + (lane >> 3);     // 0..255
      const u16* g = Wb + (size_t)(bn * 256 + vloc) * D_ + kt * 64 + (lane & 7) * 8;
      gload_lds16(g, Bs[nb] + i * 1024);
    }
  };

  auto stageBf32 = [&](int kt, int nb) {        // fallback (no ws)
    #pragma unroll
    for (int j = 0; j < 4; ++j) {
      const int vr = sr0 + 64 * j;              // 0..255
      const float* wp = Wf + (size_t)(bn * 256 + vr) * D_ + kt * 64 + sc8 * 8;
      float4 w0 = *(const float4*)wp;
      float4 w1 = *(const float4*)(wp + 4);
      union { __bf16 h[8]; i32x4 x; } pk;
      pk.h[0] = (__bf16)w0.x; pk.h[1] = (__bf16)w0.y;
      pk.h[2] = (__bf16)w0.z; pk.h[3] = (__bf16)w0.w;
      pk.h[4] = (__bf16)w1.x; pk.h[5] = (__bf16)w1.y;
      pk.h[6] = (__bf16)w1.z; pk.h[7] = (__bf16)w1.w;
      *(i32x4*)(Bs[nb] + vr * 128 + ((sc8 ^ (vr & 7)) << 4)) = pk.x;
    }
  };

  // one phase: read quadrant frags, barrier, 16 MFMA (lgkm waits by compiler)
  auto quadRead = [&](const char* Ac, const char* Bc, int ks, int mh,
                      bf16x8* af, bf16x8* bg) {
    const int kc = ks * 4 + (lane >> 4);
    #pragma unroll
    for (int mi = 0; mi < 4; ++mi) {
      const int m = wm + (mh * 4 + mi) * 16 + (lane & 15);
      af[mi] = *(const bf16x8*)(Ac + m * 128 + ((kc ^ (m & 7)) << 4));
    }
    #pragma unroll
    for (int ni = 0; ni < 4; ++ni) {
      const int n = wn + ni * 16 + (lane & 15);
      bg[ni] = *(const bf16x8*)(Bc + n * 128 + ((kc ^ (n & 7)) << 4));
    }
  };

  #define QUAD_MFMA(mh)                                                    \
    __builtin_amdgcn_s_setprio(1);                                         \
    _Pragma("unroll")                                                      \
    for (int mi = 0; mi < 4; ++mi)                                         \
      _Pragma("unroll")                                                    \
      for (int ni = 0; ni < 4; ++ni)                                       \
        acc[(mh) * 4 + mi][ni] = __builtin_amdgcn_mfma_f32_16x16x32_bf16(  \
            af[mi], bg[ni], acc[(mh) * 4 + mi][ni], 0, 0, 0);              \
    __builtin_amdgcn_s_setprio(0);

  // ---- prologue: stage K-tile 0 into buffer 0 ----
  loadA(0);
  if (USE_WS) issueB(0, 0); else stageBf32(0, 0);
  expandA(0);
  __syncthreads();

  // ---- K-loop: 8 tiles x 4 phases ----
  for (int kt = 0; kt < 8; ++kt) {
    const int cur = kt & 1, nxt = cur ^ 1;
    const char* Ac = As[cur];
    const char* Bc = Bs[cur];
    const bool pre = (kt < 7);
    bf16x8 af[4], bg[4];

    // phase 0: quadrant (ks=0, mh=0); issue next A-loads -> regs
    if (pre) loadA(kt + 1);
    quadRead(Ac, Bc, 0, 0, af, bg);
    __builtin_amdgcn_s_barrier();
    QUAD_MFMA(0)
    __builtin_amdgcn_s_barrier();

    // phase 1: quadrant (ks=0, mh=1); issue next B-DMA -> other buffer
    if (pre && USE_WS) issueB(kt + 1, nxt);
    quadRead(Ac, Bc, 0, 1, af, bg);
    __builtin_amdgcn_s_barrier();
    QUAD_MFMA(1)
    __builtin_amdgcn_s_barrier();

    // phase 2: quadrant (ks=1, mh=0); expand A after MFMA cluster so its
    // VALU overlaps in-flight MFMAs on the same wave
    quadRead(Ac, Bc, 1, 0, af, bg);
    __builtin_amdgcn_s_barrier();
    QUAD_MFMA(0)
    if (pre) {
      expandA(nxt);
      if (!USE_WS) stageBf32(kt + 1, nxt);
    }
    __builtin_amdgcn_s_barrier();

    // phase 3: quadrant (ks=1, mh=1); then buffer-flip fence
    quadRead(Ac, Bc, 1, 1, af, bg);
    __builtin_amdgcn_s_barrier();
    QUAD_MFMA(1)
    __syncthreads();   // drains B-DMA (issued 2 phases ago) + A ds_writes
  }
  #undef QUAD_MFMA

  // ---- epilogue: C/D layout col=lane&15, row=(lane>>4)*4+reg ----
  const int col = lane & 15;
  const int r4  = (lane >> 4) * 4;
  #pragma unroll
  for (int am = 0; am < 8; ++am) {
    const size_t mrow = (size_t)bm * 256 + wm + am * 16 + r4;
    float* op0 = out + mrow * V_ + bn * 256 + wn + col;
    #pragma unroll
    for (int ni = 0; ni < 4; ++ni) {
      float* op = op0 + ni * 16;
      const f32x4 v = acc[am][ni];
      op[0 * V_] = v[0] + bv[ni];
      op[1 * V_] = v[1] + bv[ni];
      op[2 * V_] = v[2] + bv[ni];
      op[3 * V_] = v[3] + bv[ni];
    }
  }
}

extern "C" void kernel_launch(void* const* d_in, const int* in_sizes, int n_in,
                              void* d_out, int out_size, void* d_ws, size_t ws_size,
                              hipStream_t stream) {
  const float* src  = (const float*)d_in[0];
  const int*   sl   = (const int*)d_in[1];
  const float* tgt  = (const float*)d_in[2];
  const int*   tl   = (const int*)d_in[3];
  const float* W    = (const float*)d_in[4];
  const float* bias = (const float*)d_in[5];
  float* out  = (float*)d_out;
  float* tail = out + (size_t)M_ * V_;

  tail_k<<<1, 64, 0, stream>>>(sl, tl, tail);

  const int grid = (M_ / 256) * (V_ / 256);   // 256 * 4 = 1024 blocks
  if (ws_size >= (size_t)V_ * D_ * sizeof(u16)) {
    prep_w<<<(V_ * D_ / 8) / 256, 256, 0, stream>>>(W, (u16*)d_ws);
    joiner_gemm<1><<<grid, 512, 0, stream>>>(
        src, tgt, (const u16*)d_ws, nullptr, bias, out);
  } else {
    joiner_gemm<0><<<grid, 512, 0, stream>>>(
        src, tgt, nullptr, W, bias, out);
  }
}

// Round 4
// 116.078 us; speedup vs baseline: 1.1346x; 1.1346x over previous
//
#include <hip/hip_runtime.h>

typedef unsigned short u16;
typedef float  f32x4  __attribute__((ext_vector_type(4)));
typedef int    i32x4  __attribute__((ext_vector_type(4)));
typedef __bf16 bf16x8 __attribute__((ext_vector_type(8)));

#define AS1 __attribute__((address_space(1)))
#define AS3 __attribute__((address_space(3)))

__device__ __forceinline__ void gload_lds16(const void* g, void* l) {
  __builtin_amdgcn_global_load_lds((AS1 void*)g, (AS3 void*)l, 16, 0, 0);
}

// Problem constants
constexpr int B_ = 8, T_ = 128, U_ = 64, D_ = 512, V_ = 1024;
constexpr int M_ = B_ * T_ * U_;   // 65536

// ---------------------------------------------------------------------------
// prep_all: one kernel does (grid >= 256):
//   blocks [0,256):       W (V,D) f32 -> bf16 ws, XOR-swizzle pre-applied
//   blocks [256,16640):   A = relu(src+tgt) -> bf16 ws, XOR-swizzle pre-applied
//   block 0, tid<16:      lengths pass-through as f32
// Swizzle: within each 64-col K-tile, 16B chunk c of row r stored at c^(r&7),
// so the GEMM can global_load_lds linearly and read with the same XOR.
// ---------------------------------------------------------------------------
__global__ void prep_all(const float* __restrict__ W,
                         const float* __restrict__ src,
                         const float* __restrict__ tgt,
                         const int* __restrict__ sl, const int* __restrict__ tl,
                         u16* __restrict__ Wb, u16* __restrict__ Aw,
                         float* __restrict__ tail) {
  if (blockIdx.x == 0 && threadIdx.x < 16) {
    const int t = threadIdx.x;
    tail[t] = (t < 8) ? (float)sl[t] : (float)tl[t - 8];
  }
  if (blockIdx.x < 256) {
    // ---- W -> bf16 swizzled ----
    const int tid = blockIdx.x * 256 + threadIdx.x;   // 65536 threads
    const int v  = tid >> 6;
    const int cs = tid & 63;
    const float* sp = W + (size_t)v * D_ + cs * 8;
    float4 w0 = *(const float4*)sp;
    float4 w1 = *(const float4*)(sp + 4);
    union { __bf16 h[8]; i32x4 x; } pk;
    pk.h[0] = (__bf16)w0.x; pk.h[1] = (__bf16)w0.y;
    pk.h[2] = (__bf16)w0.z; pk.h[3] = (__bf16)w0.w;
    pk.h[4] = (__bf16)w1.x; pk.h[5] = (__bf16)w1.y;
    pk.h[6] = (__bf16)w1.z; pk.h[7] = (__bf16)w1.w;
    const int dc = (cs >> 3) * 8 + ((cs & 7) ^ (v & 7));
    *(i32x4*)(Wb + (size_t)v * D_ + dc * 8) = pk.x;
  } else {
    // ---- A = relu(src+tgt) -> bf16 swizzled ----
    const int tid = (blockIdx.x - 256) * 256 + threadIdx.x;  // 4.19M threads
    const int m  = tid >> 6;        // joint row 0..65535 = (b*T+t)*U+u
    const int cs = tid & 63;        // 8-elem chunk
    const int bt = m >> 6;          // src row b*T+t
    const int u  = m & 63;
    const int b  = m >> 13;         // batch
    const float* sp = src + (size_t)bt * D_ + cs * 8;
    const float* tp = tgt + ((size_t)b * U_ + u) * D_ + cs * 8;
    float4 s0 = *(const float4*)sp;
    float4 s1 = *(const float4*)(sp + 4);
    float4 t0 = *(const float4*)tp;
    float4 t1 = *(const float4*)(tp + 4);
    union { __bf16 h[8]; i32x4 x; } pk;
    pk.h[0] = (__bf16)fmaxf(s0.x + t0.x, 0.f);
    pk.h[1] = (__bf16)fmaxf(s0.y + t0.y, 0.f);
    pk.h[2] = (__bf16)fmaxf(s0.z + t0.z, 0.f);
    pk.h[3] = (__bf16)fmaxf(s0.w + t0.w, 0.f);
    pk.h[4] = (__bf16)fmaxf(s1.x + t1.x, 0.f);
    pk.h[5] = (__bf16)fmaxf(s1.y + t1.y, 0.f);
    pk.h[6] = (__bf16)fmaxf(s1.z + t1.z, 0.f);
    pk.h[7] = (__bf16)fmaxf(s1.w + t1.w, 0.f);
    const int dc = (cs >> 3) * 8 + ((cs & 7) ^ (m & 7));
    *(i32x4*)(Aw + (size_t)m * D_ + dc * 8) = pk.x;
  }
}

// lengths-only kernel (fallback paths)
__global__ void tail_k(const int* __restrict__ sl, const int* __restrict__ tl,
                       float* __restrict__ tail) {
  const int t = threadIdx.x;
  if (t < 8)       tail[t] = (float)sl[t];
  else if (t < 16) tail[t] = (float)tl[t - 8];
}

// ---------------------------------------------------------------------------
// Main GEMM (ws path): C = A_bf16 x W_bf16^T + bias.
// BM=BN=128, BK=64, 256 threads (4 waves 2x2), wave tile 64x64,
// 4x4 x mfma_f32_16x16x32_bf16. Both operands staged by global_load_lds
// (zero staging VALU/VGPR). Double-buffered LDS (64 KB, 2 blocks/CU).
// One __syncthreads per K-tile: its vmcnt(0) drains DMAs issued a full
// compute phase earlier (aged drain), and hands off the other buffer.
// XCD swizzle: 8 N-blocks of one M-tile land on the same XCD -> A-tile
// served from that XCD's L2.
// ---------------------------------------------------------------------------
__global__ __launch_bounds__(256, 2) void joiner_gemm_ws(
    const u16* __restrict__ Aw, const u16* __restrict__ Wb,
    const float* __restrict__ bias, float* __restrict__ out)
{
  __shared__ __align__(16) char As[2][16384];
  __shared__ __align__(16) char Bs[2][16384];

  const int tid  = threadIdx.x;
  const int lane = tid & 63;
  const int wid  = tid >> 6;
  // XCD-aware swizzle: xcd = wgid&7 gets contiguous chunk of 64 bm x 8 bn
  const int wgid = blockIdx.x;
  const int xcd  = wgid & 7;
  const int j    = wgid >> 3;          // 0..511
  const int bm   = xcd * 64 + (j >> 3);
  const int bn   = j & 7;
  const int wm   = (wid >> 1) * 64;
  const int wn   = (wid & 1) * 64;

  f32x4 acc[4][4] = {};

  float bv[4];
  #pragma unroll
  for (int ni = 0; ni < 4; ++ni)
    bv[ni] = bias[bn * 128 + wn + ni * 16 + (lane & 15)];

  auto issueA = [&](int kt, int nb) {
    #pragma unroll
    for (int q = 0; q < 4; ++q) {
      const int i   = wid * 4 + q;            // 16 x 1KB stripes
      const int row = i * 8 + (lane >> 3);    // 0..127
      const u16* g = Aw + (size_t)(bm * 128 + row) * D_ + kt * 64 + (lane & 7) * 8;
      gload_lds16(g, As[nb] + i * 1024);
    }
  };
  auto issueB = [&](int kt, int nb) {
    #pragma unroll
    for (int q = 0; q < 4; ++q) {
      const int i   = wid * 4 + q;
      const int row = i * 8 + (lane >> 3);
      const u16* g = Wb + (size_t)(bn * 128 + row) * D_ + kt * 64 + (lane & 7) * 8;
      gload_lds16(g, Bs[nb] + i * 1024);
    }
  };

  auto compute = [&](int cb) {
    #pragma unroll
    for (int s = 0; s < 2; ++s) {
      const int kc = s * 4 + (lane >> 4);   // 16B k-chunk index
      bf16x8 af[4], bg[4];
      #pragma unroll
      for (int mi = 0; mi < 4; ++mi) {
        const int r = wm + mi * 16 + (lane & 15);
        af[mi] = *(const bf16x8*)(As[cb] + r * 128 + ((kc ^ (r & 7)) << 4));
      }
      #pragma unroll
      for (int ni = 0; ni < 4; ++ni) {
        const int n = wn + ni * 16 + (lane & 15);
        bg[ni] = *(const bf16x8*)(Bs[cb] + n * 128 + ((kc ^ (n & 7)) << 4));
      }
      __builtin_amdgcn_s_setprio(1);
      #pragma unroll
      for (int mi = 0; mi < 4; ++mi)
        #pragma unroll
        for (int ni = 0; ni < 4; ++ni)
          acc[mi][ni] = __builtin_amdgcn_mfma_f32_16x16x32_bf16(
              af[mi], bg[ni], acc[mi][ni], 0, 0, 0);
      __builtin_amdgcn_s_setprio(0);
    }
  };

  // prologue: DMA K-tile 0 -> buf 0
  issueA(0, 0); issueB(0, 0);

  for (int kt = 0; kt < 8; ++kt) {
    const int cur = kt & 1;
    __syncthreads();                 // drain aged DMAs for buf[cur]; handoff
    if (kt < 7) { issueA(kt + 1, cur ^ 1); issueB(kt + 1, cur ^ 1); }
    compute(cur);
  }

  // epilogue: C/D layout col=lane&15, row=(lane>>4)*4+reg
  const int col = lane & 15;
  const int r4  = (lane >> 4) * 4;
  #pragma unroll
  for (int mi = 0; mi < 4; ++mi) {
    const size_t mrow = (size_t)bm * 128 + wm + mi * 16 + r4;
    float* op0 = out + mrow * V_ + bn * 128 + wn + col;
    #pragma unroll
    for (int ni = 0; ni < 4; ++ni) {
      float* op = op0 + ni * 16;
      const f32x4 v = acc[mi][ni];
      op[0 * V_] = v[0] + bv[ni];
      op[1 * V_] = v[1] + bv[ni];
      op[2 * V_] = v[2] + bv[ni];
      op[3 * V_] = v[3] + bv[ni];
    }
  }
}

// ---------------------------------------------------------------------------
// Fallback (ws too small for A): round-1 fused kernel, f32 W in-loop.
// ---------------------------------------------------------------------------
__global__ __launch_bounds__(256, 2) void joiner_gemm_f32(
    const float* __restrict__ src, const float* __restrict__ tgt,
    const float* __restrict__ Wf, const float* __restrict__ bias,
    float* __restrict__ out)
{
  __shared__ char As[128 * 128];
  __shared__ char Bs[128 * 128];

  const int tid  = threadIdx.x;
  const int lane = tid & 63;
  const int wid  = tid >> 6;
  const int bn   = blockIdx.x & 7;
  const int bm   = blockIdx.x >> 3;
  const int bt0  = bm * 2;
  const int bb   = bt0 >> 7;
  const int sr0  = tid >> 3;
  const int sc8  = tid & 7;
  const int wm   = (wid >> 1) * 64;
  const int wn   = (wid & 1) * 64;

  f32x4 acc[4][4] = {};

  const float* srcp0 = src + (size_t)bt0 * D_ + sc8 * 8;
  const float* srcp1 = srcp0 + D_;
  const float* tgtp0 = tgt + ((size_t)bb * U_ + sr0) * D_ + sc8 * 8;
  const float* tgtp1 = tgtp0 + (size_t)32 * D_;

  for (int kt = 0; kt < 8; ++kt) {
    const int k0 = kt * 64;
    #pragma unroll
    for (int jj = 0; jj < 4; ++jj) {
      const int vr = sr0 + 32 * jj;
      const float* wp = Wf + (size_t)(bn * 128 + vr) * D_ + k0 + sc8 * 8;
      float4 w0 = *(const float4*)wp;
      float4 w1 = *(const float4*)(wp + 4);
      union { __bf16 h[8]; i32x4 x; } pk;
      pk.h[0] = (__bf16)w0.x; pk.h[1] = (__bf16)w0.y;
      pk.h[2] = (__bf16)w0.z; pk.h[3] = (__bf16)w0.w;
      pk.h[4] = (__bf16)w1.x; pk.h[5] = (__bf16)w1.y;
      pk.h[6] = (__bf16)w1.z; pk.h[7] = (__bf16)w1.w;
      *(i32x4*)(Bs + vr * 128 + ((sc8 ^ (vr & 7)) << 4)) = pk.x;
    }
    float4 s0a = *(const float4*)(srcp0 + k0), s0b = *(const float4*)(srcp0 + k0 + 4);
    float4 s1a = *(const float4*)(srcp1 + k0), s1b = *(const float4*)(srcp1 + k0 + 4);
    float4 t0a = *(const float4*)(tgtp0 + k0), t0b = *(const float4*)(tgtp0 + k0 + 4);
    float4 t1a = *(const float4*)(tgtp1 + k0), t1b = *(const float4*)(tgtp1 + k0 + 4);
    #pragma unroll
    for (int i = 0; i < 2; ++i) {
      const float4 sa = i ? s1a : s0a;
      const float4 sb = i ? s1b : s0b;
      #pragma unroll
      for (int jj = 0; jj < 2; ++jj) {
        const float4 ta = jj ? t1a : t0a;
        const float4 tb = jj ? t1b : t0b;
        const int r = i * 64 + jj * 32 + sr0;
        union { __bf16 h[8]; i32x4 x; } pk;
        pk.h[0] = (__bf16)fmaxf(sa.x + ta.x, 0.f);
        pk.h[1] = (__bf16)fmaxf(sa.y + ta.y, 0.f);
        pk.h[2] = (__bf16)fmaxf(sa.z + ta.z, 0.f);
        pk.h[3] = (__bf16)fmaxf(sa.w + ta.w, 0.f);
        pk.h[4] = (__bf16)fmaxf(sb.x + tb.x, 0.f);
        pk.h[5] = (__bf16)fmaxf(sb.y + tb.y, 0.f);
        pk.h[6] = (__bf16)fmaxf(sb.z + tb.z, 0.f);
        pk.h[7] = (__bf16)fmaxf(sb.w + tb.w, 0.f);
        *(i32x4*)(As + r * 128 + ((sc8 ^ (r & 7)) << 4)) = pk.x;
      }
    }
    __syncthreads();
    #pragma unroll
    for (int s = 0; s < 2; ++s) {
      const int kc = s * 4 + (lane >> 4);
      bf16x8 af[4], bg[4];
      #pragma unroll
      for (int mi = 0; mi < 4; ++mi) {
        const int r = wm + mi * 16 + (lane & 15);
        af[mi] = *(const bf16x8*)(As + r * 128 + ((kc ^ (r & 7)) << 4));
      }
      #pragma unroll
      for (int ni = 0; ni < 4; ++ni) {
        const int n = wn + ni * 16 + (lane & 15);
        bg[ni] = *(const bf16x8*)(Bs + n * 128 + ((kc ^ (n & 7)) << 4));
      }
      #pragma unroll
      for (int mi = 0; mi < 4; ++mi)
        #pragma unroll
        for (int ni = 0; ni < 4; ++ni)
          acc[mi][ni] = __builtin_amdgcn_mfma_f32_16x16x32_bf16(
              af[mi], bg[ni], acc[mi][ni], 0, 0, 0);
    }
    __syncthreads();
  }

  const int col = lane & 15;
  const int r4  = (lane >> 4) * 4;
  float bv[4];
  #pragma unroll
  for (int ni = 0; ni < 4; ++ni) bv[ni] = bias[bn * 128 + wn + ni * 16 + col];
  #pragma unroll
  for (int mi = 0; mi < 4; ++mi) {
    const size_t mrow = (size_t)bm * 128 + wm + mi * 16 + r4;
    float* op0 = out + mrow * V_ + bn * 128 + wn + col;
    #pragma unroll
    for (int ni = 0; ni < 4; ++ni) {
      float* op = op0 + ni * 16;
      const f32x4 v = acc[mi][ni];
      op[0 * V_] = v[0] + bv[ni];
      op[1 * V_] = v[1] + bv[ni];
      op[2 * V_] = v[2] + bv[ni];
      op[3 * V_] = v[3] + bv[ni];
    }
  }
}

extern "C" void kernel_launch(void* const* d_in, const int* in_sizes, int n_in,
                              void* d_out, int out_size, void* d_ws, size_t ws_size,
                              hipStream_t stream) {
  const float* src  = (const float*)d_in[0];
  const int*   sl   = (const int*)d_in[1];
  const float* tgt  = (const float*)d_in[2];
  const int*   tl   = (const int*)d_in[3];
  const float* W    = (const float*)d_in[4];
  const float* bias = (const float*)d_in[5];
  float* out  = (float*)d_out;
  float* tail = out + (size_t)M_ * V_;

  const size_t needW = (size_t)V_ * D_ * sizeof(u16);            // 1 MB
  const size_t needA = (size_t)M_ * D_ * sizeof(u16);            // 64 MB

  if (ws_size >= needW + needA) {
    u16* Wb = (u16*)d_ws;
    u16* Aw = Wb + (size_t)V_ * D_;
    prep_all<<<256 + M_ * 64 / 256, 256, 0, stream>>>(W, src, tgt, sl, tl, Wb, Aw, tail);
    joiner_gemm_ws<<<(M_ / 128) * (V_ / 128), 256, 0, stream>>>(Aw, Wb, bias, out);
  } else {
    tail_k<<<1, 64, 0, stream>>>(sl, tl, tail);
    joiner_gemm_f32<<<(M_ / 128) * (V_ / 128), 256, 0, stream>>>(src, tgt, W, bias, out);
  }
}